// Round 8
// baseline (668.087 us; speedup 1.0000x reference)
//
#include <hip/hip_runtime.h>
#include <hip/hip_bf16.h>

// ShockPropagationGNN — round 7: fewer kernels, grid-stride dispatch shapes.
// - logits fused into gout (al = h_tile @ vat via MFMA) and into encoder (L0).
// - encoder grid-stride 512 blocks, weights+va0 in LDS.
// - aggregate grid-stride 1536 blocks with (s, al, h-row) prefetch.
// 12 kernels total (was 15).

#define N_NODES 50000
#define N_EDGES 200000
#define ETOT    (N_EDGES + N_NODES)
#define HID     128
#define LN_EPS  1e-5f
#define NEG     0.2f

typedef __hip_bfloat16 bf16;
typedef __attribute__((ext_vector_type(8))) short v8s;
typedef __attribute__((ext_vector_type(4))) float v4f;
#define MFMA(a, b, c) __builtin_amdgcn_mfma_f32_16x16x32_bf16(a, b, c, 0, 0, 0)

__device__ __forceinline__ float b2f(unsigned short s) {
    return __uint_as_float(((unsigned int)s) << 16);
}
__device__ __forceinline__ unsigned short f2b(float f) {
    __hip_bfloat16 h = __float2bfloat16(f);
    return *reinterpret_cast<unsigned short*>(&h);
}
__device__ __forceinline__ unsigned int pack2(float a, float b) {
    return (unsigned int)f2b(a) | ((unsigned int)f2b(b) << 16);
}
__device__ __forceinline__ float pread(const void* p, size_t i, int isbf) {
    if (isbf) return b2f(((const unsigned short*)p)[i]);
    return ((const float*)p)[i];
}

__global__ void k_fill(float* out, int n, float v) {
    int i = blockIdx.x * blockDim.x + threadIdx.x;
    if (i < n) out[i] = v;
}

// ------------------------------------------------------------ dtype detect
__global__ void k_detect(const unsigned short* __restrict__ xbuf,
                         int* __restrict__ flag) {
    int sane = 0;
    for (int j = threadIdx.x; j < 4096; j += 64) {
        unsigned short v = xbuf[2 * j];
        int e = (v >> 7) & 0xFF;
        if (v == 0 || (e > 96 && e < 160)) sane++;
    }
    for (int off = 32; off > 0; off >>= 1) sane += __shfl_down(sane, off);
    if (threadIdx.x == 0) flag[0] = (sane * 10 >= 4096 * 9) ? 1 : 0;
}

// ------------------------------------------------------------ prep (fused)
struct PrepArgs {
    const void *encw, *encb, *enlg, *enlb, *gatw, *asrc, *adst, *bias,
               *bng, *bnb, *bnm, *bnv, *em1w, *em1b, *emlg, *emlb,
               *em2w, *em2b, *em3w, *em3b;
};
#define PREP_ITEMS (150000 + 8193 + 196608 + 36864 + 8192 + 3072 + 6144)
__global__ void k_prep(PrepArgs a, float* __restrict__ pool,
                       unsigned short* __restrict__ gwt,   // gw2t[L][c=128][hk=512]
                       unsigned short* __restrict__ w1t,
                       unsigned short* __restrict__ w2t,
                       float* __restrict__ va,             // [L][k=128][8] fp32
                       unsigned short* __restrict__ vat,   // [L][n=16][k=128] bf16
                       float* __restrict__ down, int* __restrict__ deg,
                       int* __restrict__ fill, const int* __restrict__ flag) {
    int i = blockIdx.x * 256 + threadIdx.x;
    int bf = flag[0];
    if (i < 150000) {
        int which = i / 50000, idx = i - which * 50000;
        if (which == 0) down[idx] = 0.f;
        else if (which == 1) deg[idx] = 0;
        else fill[idx] = 0;
        return;
    }
    i -= 150000;
    if (i < 8193) {
        const void* s; int off;
        if      (i < 2304) { s = a.encw; off = 0;    }
        else if (i < 2432) { s = a.encb; off = 2304; }
        else if (i < 2560) { s = a.enlg; off = 2432; }
        else if (i < 2688) { s = a.enlb; off = 2560; }
        else if (i < 4224) { s = a.asrc; off = 2688; }
        else if (i < 5760) { s = a.adst; off = 4224; }
        else if (i < 6144) { s = a.bias; off = 5760; }
        else if (i < 6528) { s = a.bng;  off = 6144; }
        else if (i < 6912) { s = a.bnb;  off = 6528; }
        else if (i < 7296) { s = a.bnm;  off = 6912; }
        else if (i < 7680) { s = a.bnv;  off = 7296; }
        else if (i < 7808) { s = a.em1b; off = 7680; }
        else if (i < 7936) { s = a.emlg; off = 7808; }
        else if (i < 8064) { s = a.emlb; off = 7936; }
        else if (i < 8128) { s = a.em2b; off = 8064; }
        else if (i < 8192) { s = a.em3w; off = 8128; }
        else               { s = a.em3b; off = 8192; }
        pool[i] = pread(s, i - off, bf);
        return;
    }
    i -= 8193;
    if (i < 196608) {   // gw2t[L][c][hk] = gat_w[L][k][h*128+c]
        int L = i >> 16, rem = i & 65535;
        int c = rem >> 9, hk = rem & 511, hh = hk >> 7, k = hk & 127;
        gwt[i] = f2b(pread(a.gatw,
            (size_t)L * 65536 + (size_t)k * 512 + hh * 128 + c, bf));
        return;
    }
    i -= 196608;
    if (i < 36864) {    // w1t[n=128][k=288] = em1_w[k][n], zero-pad k>=264
        int n = i / 288, k = i - n * 288;
        w1t[i] = (k < 264) ? f2b(pread(a.em1w, (size_t)k * 128 + n, bf)) : 0;
        return;
    }
    i -= 36864;
    if (i < 8192) {     // w2t[n=64][k=128] = em2_w[k][n]
        int n = i >> 7, k = i & 127;
        w2t[i] = f2b(pread(a.em2w, (size_t)k * 64 + n, bf));
        return;
    }
    i -= 8192;
    if (i < 3072) {     // va[L][k][j8] = sum_c W[L][k][h*128+c] * att[h][c]
        int L = i / 1024, rem = i - L * 1024;
        int k = rem >> 3, j8 = rem & 7, hh = j8 & 3, sd = j8 >> 2;
        const void* att = sd ? a.adst : a.asrc;
        float s = 0.f;
        for (int c = 0; c < 128; c++)
            s += pread(a.gatw, (size_t)L * 65536 + (size_t)k * 512 + hh * 128 + c, bf)
               * pread(att, (size_t)L * 512 + hh * 128 + c, bf);
        va[i] = s;
        return;
    }
    i -= 3072;
    if (i < 6144) {     // vat[L][n=16][k=128] bf16, n<8 real (j), else 0
        int L = i / 2048, rem = i - L * 2048;
        int n = rem >> 7, k = rem & 127;
        if (n >= 8) { vat[i] = 0; return; }
        int hh = n & 3, sd = n >> 2;
        const void* att = sd ? a.adst : a.asrc;
        float s = 0.f;
        for (int c = 0; c < 128; c++)
            s += pread(a.gatw, (size_t)L * 65536 + (size_t)k * 512 + hh * 128 + c, bf)
               * pread(att, (size_t)L * 512 + hh * 128 + c, bf);
        vat[i] = f2b(s);
    }
}

// ------------------------------------------------------------ graph build
__global__ void k_graph(const int* __restrict__ ei, const int* __restrict__ shock,
                        float* __restrict__ down, int* __restrict__ deg) {
    int e = blockIdx.x * blockDim.x + threadIdx.x;
    if (e < ETOT) {
        int d = (e < N_EDGES) ? ei[N_EDGES + e] : (e - N_EDGES);
        atomicAdd(&deg[d], 1);
        if (e < N_EDGES && shock[ei[e]] != 0) down[d] = 1.f;
    }
}

__global__ __launch_bounds__(1024) void k_scan(
        const int* __restrict__ deg, int* __restrict__ row_start) {
    __shared__ int wsum[16];
    __shared__ int wexcl[16];
    const int PER = 49;
    int t = threadIdx.x, lane = t & 63, wid = t >> 6;
    int base = t * PER;
    int tot = 0;
    for (int i = 0; i < PER; i++) {
        int idx = base + i;
        if (idx < N_NODES) tot += deg[idx];
    }
    int inc = tot;
#pragma unroll
    for (int off = 1; off < 64; off <<= 1) {
        int v = __shfl_up(inc, off);
        if (lane >= off) inc += v;
    }
    if (lane == 63) wsum[wid] = inc;
    __syncthreads();
    if (wid == 0) {
        int wv = (lane < 16) ? wsum[lane] : 0;
        int winc = wv;
#pragma unroll
        for (int off = 1; off < 16; off <<= 1) {
            int v = __shfl_up(winc, off);
            if (lane >= off) winc += v;
        }
        if (lane < 16) wexcl[lane] = winc - wv;
    }
    __syncthreads();
    int run = wexcl[wid] + (inc - tot);
    for (int i = 0; i < PER; i++) {
        int idx = base + i;
        if (idx < N_NODES) {
            row_start[idx] = run;
            run += deg[idx];
        }
    }
    if (t == 0) row_start[N_NODES] = ETOT;
}

__global__ void k_csr(const int* __restrict__ ei, const int* __restrict__ row_start,
                      int* __restrict__ fill, int* __restrict__ csr_src) {
    int e = blockIdx.x * blockDim.x + threadIdx.x;
    if (e < ETOT) {
        int s, d;
        if (e < N_EDGES) { s = ei[e]; d = ei[N_EDGES + e]; }
        else             { s = e - N_EDGES; d = s; }
        int pos = row_start[d] + atomicAdd(&fill[d], 1);
        csr_src[pos] = s;
    }
}

// ------------------------------------------------------------ encoder -> h, al0
// grid-stride 512 blocks x 256 thr; 2 nodes per iteration (t>>7 = node slot).
// enc weights + va0 staged in LDS once. al0 fused (wave per node).
__global__ __launch_bounds__(256) void k_encoder(
        const void* __restrict__ xraw, const int* __restrict__ flag,
        const int* __restrict__ shock, const float* __restrict__ down,
        const float* __restrict__ enc_w, const float* __restrict__ enc_b,
        const float* __restrict__ ln_g, const float* __restrict__ ln_b,
        const float* __restrict__ va0,
        unsigned short* __restrict__ h, float* __restrict__ al) {
    __shared__ float sw[2304];
    __shared__ float sb[128], sg[128], sbt[128];
    __shared__ float sva[1024];
    __shared__ float xa[2][18];
    __shared__ float red[2][2][2];
    __shared__ float hrow[2][128];
    int t = threadIdx.x;
    for (int i = t; i < 2304; i += 256) sw[i] = enc_w[i];
    for (int i = t; i < 1024; i += 256) sva[i] = va0[i];
    if (t < 128) { sb[t] = enc_b[t]; sg[t] = ln_g[t]; sbt[t] = ln_b[t]; }
    __syncthreads();

    int sub = t >> 7, c = t & 127;
    int wih = (t >> 6) & 1;    // wave within half
    int bf = flag[0];
    for (int pair = blockIdx.x; pair < N_NODES / 2; pair += gridDim.x) {
        int n = pair * 2 + sub;
        if (c < 16)       xa[sub][c]  = pread(xraw, (size_t)n * 16 + c, bf);
        else if (c == 16) xa[sub][16] = (float)shock[n];
        else if (c == 17) xa[sub][17] = down[n];
        __syncthreads();
        float acc = sb[c];
#pragma unroll
        for (int k = 0; k < 18; k++) acc = fmaf(xa[sub][k], sw[k * HID + c], acc);
        float s = acc, q = acc * acc;
        for (int off = 32; off > 0; off >>= 1) {
            s += __shfl_down(s, off);
            q += __shfl_down(q, off);
        }
        if ((t & 63) == 0) { red[sub][wih][0] = s; red[sub][wih][1] = q; }
        __syncthreads();
        float S = red[sub][0][0] + red[sub][1][0];
        float Q = red[sub][0][1] + red[sub][1][1];
        float mu = S * (1.f / 128.f);
        float var = Q * (1.f / 128.f) - mu * mu;
        float rstd = rsqrtf(var + LN_EPS);
        float v = fmaxf((acc - mu) * rstd * sg[c] + sbt[c], 0.f);
        h[(size_t)n * HID + c] = f2b(v);
        hrow[sub][c] = v;
        __syncthreads();
        // al0: wave 0 -> node pair*2, wave 2 -> node pair*2+1
        if ((t & 64) == 0) {
            int nn = pair * 2 + (t >> 7);
            int l = t & 63, j = l & 7, half = l >> 3;
            float p = 0.f;
#pragma unroll
            for (int i = 0; i < 16; i++) {
                int cc = half * 16 + i;
                p = fmaf(hrow[t >> 7][cc], sva[cc * 8 + j], p);
            }
            p += __shfl_xor(p, 8);
            p += __shfl_xor(p, 16);
            p += __shfl_xor(p, 32);
            if (l < 8) al[(size_t)nn * 8 + j] = p;
        }
        __syncthreads();
    }
}

// ------------------------------------------------------------ aggregation -> g
// grid-stride, wave per node, prefetched (s, al4, h-row) chain.
__global__ __launch_bounds__(256) void k_aggregate(
        const unsigned short* __restrict__ h, const float* __restrict__ al,
        const int* __restrict__ row_start, const int* __restrict__ csr_src,
        unsigned short* __restrict__ g) {
    int w = threadIdx.x >> 6, l = threadIdx.x & 63;
    for (int n = blockIdx.x * 4 + w; n < N_NODES; n += gridDim.x * 4) {
        int r0 = row_start[n], r1 = row_start[n + 1];
        float4 ad = *(const float4*)(al + (size_t)n * 8 + 4);
        float den[4] = {};
        float acc[4][2] = {};
        int s = csr_src[r0];                       // deg >= 1 (self loop)
        float4 as = *(const float4*)(al + (size_t)s * 8);
        unsigned int hv = *(const unsigned int*)&h[(size_t)s * 128 + 2 * l];
        for (int j = r0; j < r1; j++) {
            int s2 = s; float4 as2 = as; unsigned int hv2 = hv;
            if (j + 1 < r1) {
                s2 = csr_src[j + 1];
                as2 = *(const float4*)(al + (size_t)s2 * 8);
                hv2 = *(const unsigned int*)&h[(size_t)s2 * 128 + 2 * l];
            }
            float h0 = b2f(hv & 0xffff), h1 = b2f(hv >> 16);
            float lg[4] = {as.x + ad.x, as.y + ad.y, as.z + ad.z, as.w + ad.w};
#pragma unroll
            for (int hh = 0; hh < 4; hh++) {
                float a = lg[hh];
                a = (a >= 0.f) ? a : NEG * a;
                float we = __expf(a);
                den[hh] += we;
                acc[hh][0] = fmaf(we, h0, acc[hh][0]);
                acc[hh][1] = fmaf(we, h1, acc[hh][1]);
            }
            s = s2; as = as2; hv = hv2;
        }
#pragma unroll
        for (int hh = 0; hh < 4; hh++) {
            float sc = 0.25f / (den[hh] + 1e-16f);
            *(unsigned int*)&g[(size_t)n * 512 + hh * 128 + 2 * l] =
                pack2(acc[hh][0] * sc, acc[hh][1] * sc);
        }
    }
}

// ------------------------------------------------------------ output GEMM + al
// h = BN(g @ Bt^T + bias); then al_next = h_tile @ vat (one MFMA pass).
__global__ __launch_bounds__(256, 2) void k_gout(
        const unsigned short* __restrict__ g, const unsigned short* __restrict__ Bt,
        const float* __restrict__ bias,
        const float* __restrict__ bn_g, const float* __restrict__ bn_b,
        const float* __restrict__ bn_m, const float* __restrict__ bn_v,
        const unsigned short* __restrict__ vatL,   // null-like skip via do_al
        unsigned short* __restrict__ h, float* __restrict__ al,
        int relu_flag, int do_al) {
    __shared__ __align__(16) unsigned short As[2][64 * 136];
    int t = threadIdx.x;
    int lane = t & 63, w = t >> 6, l15 = lane & 15, q = lane >> 4;
    int m0 = blockIdx.x * 64;
    int c0 = w * 32 + 2 * l15, c1 = c0 + 1;

#pragma unroll
    for (int it = 0; it < 4; it++) {
        int u = t + it * 256;
        int row = u >> 4, ch = u & 15;
        v8s val = {0, 0, 0, 0, 0, 0, 0, 0};
        if (m0 + row < N_NODES)
            val = *(const v8s*)&g[(size_t)(m0 + row) * 512 + ch * 8];
        *(v8s*)&As[0][row * 136 + ch * 8] = val;
    }

    v4f acc[4][2] = {};
    for (int kc = 0; kc < 4; kc++) {
        v8s b[2][4];
#pragma unroll
        for (int nt = 0; nt < 2; nt++)
#pragma unroll
            for (int kt = 0; kt < 4; kt++)
                b[nt][kt] = *(const v8s*)&Bt[(size_t)(c0 + nt) * 512
                                             + kc * 128 + kt * 32 + q * 8];
        v8s st[4];
        if (kc < 3) {
#pragma unroll
            for (int it = 0; it < 4; it++) {
                int u = t + it * 256;
                int row = u >> 4, ch = u & 15;
                v8s val = {0, 0, 0, 0, 0, 0, 0, 0};
                if (m0 + row < N_NODES)
                    val = *(const v8s*)&g[(size_t)(m0 + row) * 512
                                          + (kc + 1) * 128 + ch * 8];
                st[it] = val;
            }
        }
        __syncthreads();
        const unsigned short* Ab = As[kc & 1];
#pragma unroll
        for (int kt = 0; kt < 4; kt++)
#pragma unroll
            for (int mt = 0; mt < 4; mt++) {
                v8s a = *(const v8s*)&Ab[(mt * 16 + l15) * 136 + kt * 32 + q * 8];
                acc[mt][0] = MFMA(a, b[0][kt], acc[mt][0]);
                acc[mt][1] = MFMA(a, b[1][kt], acc[mt][1]);
            }
        if (kc < 3) {
#pragma unroll
            for (int it = 0; it < 4; it++) {
                int u = t + it * 256;
                int row = u >> 4, ch = u & 15;
                *(v8s*)&As[(kc + 1) & 1][row * 136 + ch * 8] = st[it];
            }
        }
    }

    // epilogue: bias + BN (+relu); keep final bf16 pair in regs
    float rs0 = rsqrtf(bn_v[c0] + LN_EPS) * bn_g[c0];
    float sh0 = bn_b[c0] + (bias[c0] - bn_m[c0]) * rs0;
    float rs1 = rsqrtf(bn_v[c1] + LN_EPS) * bn_g[c1];
    float sh1 = bn_b[c1] + (bias[c1] - bn_m[c1]) * rs1;
    unsigned int hp[4][4];
#pragma unroll
    for (int mt = 0; mt < 4; mt++)
#pragma unroll
        for (int r = 0; r < 4; r++) {
            float v0 = acc[mt][0][r] * rs0 + sh0;
            float v1 = acc[mt][1][r] * rs1 + sh1;
            if (relu_flag) { v0 = fmaxf(v0, 0.f); v1 = fmaxf(v1, 0.f); }
            hp[mt][r] = pack2(v0, v1);
            int node = m0 + mt * 16 + q * 4 + r;
            if (node < N_NODES)
                *(unsigned int*)&h[(size_t)node * 128 + c0] = hp[mt][r];
        }

    if (do_al) {
        __syncthreads();     // all As reads done
#pragma unroll
        for (int mt = 0; mt < 4; mt++)
#pragma unroll
            for (int r = 0; r < 4; r++)
                *(unsigned int*)&As[0][(mt * 16 + q * 4 + r) * 136 + c0] = hp[mt][r];
        __syncthreads();
        v8s bv[4];
#pragma unroll
        for (int kt = 0; kt < 4; kt++)
            bv[kt] = *(const v8s*)&vatL[l15 * 128 + kt * 32 + q * 8];
        v4f aal = {};
#pragma unroll
        for (int kt = 0; kt < 4; kt++) {
            v8s a = *(const v8s*)&As[0][(w * 16 + l15) * 136 + kt * 32 + q * 8];
            aal = MFMA(a, bv[kt], aal);
        }
        if (l15 < 8) {
#pragma unroll
            for (int r = 0; r < 4; r++) {
                int node = m0 + w * 16 + q * 4 + r;
                if (node < N_NODES) al[(size_t)node * 8 + l15] = aal[r];
            }
        }
    }
}

// ------------------------------------------------------------ edge MLP (MFMA)
__global__ __launch_bounds__(256, 4) void k_edgemlp(
        const unsigned short* __restrict__ h, const int* __restrict__ ei,
        const void* __restrict__ eraw, const int* __restrict__ flag,
        const unsigned short* __restrict__ w1t, const unsigned short* __restrict__ w2t,
        const float* __restrict__ em1b, const float* __restrict__ lng,
        const float* __restrict__ lnb, const float* __restrict__ em2b,
        const float* __restrict__ em3w, const float* __restrict__ em3b,
        float* __restrict__ out) {
    __shared__ __align__(16) unsigned short in_s[64 * 296];
    __shared__ float sums[64][4][2];
    __shared__ float stats[64][2];
    __shared__ int   idx_s[128];
    unsigned short* za = in_s;
    float* part = &sums[0][0][0];

    int t = threadIdx.x;
    int lane = t & 63, w = t >> 6, l15 = lane & 15, q = lane >> 4;
    int e0 = blockIdx.x * 64;
    int bf = flag[0];
    int c0 = w * 32 + 2 * l15, c1 = c0 + 1;

    v8s b1[2][9];
#pragma unroll
    for (int nt = 0; nt < 2; nt++)
#pragma unroll
        for (int kt = 0; kt < 9; kt++)
            b1[nt][kt] = *(const v8s*)&w1t[(size_t)(c0 + nt) * 288 + kt * 32 + q * 8];
    v8s b2[4];
#pragma unroll
    for (int kt = 0; kt < 4; kt++)
        b2[kt] = *(const v8s*)&w2t[(size_t)(w * 16 + l15) * 128 + kt * 32 + q * 8];

    float bc0 = em1b[c0], bc1 = em1b[c1];
    float lg0 = lng[c0], lg1 = lng[c1], lb0 = lnb[c0], lb1 = lnb[c1];

    if (t < 64) {
        idx_s[t * 2]     = ei[e0 + t];
        idx_s[t * 2 + 1] = ei[N_EDGES + e0 + t];
    }
    __syncthreads();

    for (int idx = t; idx < 64 * 36; idx += 256) {
        int row = idx / 36, c = idx - row * 36;
        v8s val = {0, 0, 0, 0, 0, 0, 0, 0};
        if (c < 32) {
            int node = idx_s[row * 2 + (c >> 4)];
            val = *(const v8s*)&h[(size_t)node * 128 + (c & 15) * 8];
        } else if (c == 32) {
            size_t eb = (size_t)(e0 + row) * 8;
            if (bf) {
                val = *(const v8s*)((const unsigned short*)eraw + eb);
            } else {
                short tmp[8];
#pragma unroll
                for (int j = 0; j < 8; j++)
                    tmp[j] = (short)f2b(((const float*)eraw)[eb + j]);
                val = *(const v8s*)tmp;
            }
        }
        *(v8s*)&in_s[row * 296 + c * 8] = val;
    }
    __syncthreads();

    v4f acc1[4][2] = {};
#pragma unroll
    for (int kt = 0; kt < 9; kt++)
#pragma unroll
        for (int mt = 0; mt < 4; mt++) {
            v8s a = *(const v8s*)&in_s[(mt * 16 + l15) * 296 + kt * 32 + q * 8];
            acc1[mt][0] = MFMA(a, b1[0][kt], acc1[mt][0]);
            acc1[mt][1] = MFMA(a, b1[1][kt], acc1[mt][1]);
        }

#pragma unroll
    for (int mt = 0; mt < 4; mt++)
#pragma unroll
        for (int r = 0; r < 4; r++) {
            float v0 = acc1[mt][0][r] + bc0;
            float v1 = acc1[mt][1][r] + bc1;
            float s = v0 + v1;
            float qq = v0 * v0 + v1 * v1;
#pragma unroll
            for (int off = 1; off < 16; off <<= 1) {
                s  += __shfl_xor(s, off);
                qq += __shfl_xor(qq, off);
            }
            if (l15 == 0) {
                sums[mt * 16 + q * 4 + r][w][0] = s;
                sums[mt * 16 + q * 4 + r][w][1] = qq;
            }
        }
    __syncthreads();
    if (t < 64) {
        float S = sums[t][0][0] + sums[t][1][0] + sums[t][2][0] + sums[t][3][0];
        float Q = sums[t][0][1] + sums[t][1][1] + sums[t][2][1] + sums[t][3][1];
        float mu = S * (1.f / 128.f);
        float var = Q * (1.f / 128.f) - mu * mu;
        stats[t][0] = mu;
        stats[t][1] = rsqrtf(var + LN_EPS);
    }
    __syncthreads();

#pragma unroll
    for (int mt = 0; mt < 4; mt++)
#pragma unroll
        for (int r = 0; r < 4; r++) {
            int row = mt * 16 + q * 4 + r;
            float mu = stats[row][0], rstd = stats[row][1];
            float z0 = (acc1[mt][0][r] + bc0 - mu) * rstd * lg0 + lb0;
            float z1 = (acc1[mt][1][r] + bc1 - mu) * rstd * lg1 + lb1;
            *(unsigned int*)&za[row * 136 + c0] =
                pack2(fmaxf(z0, 0.f), fmaxf(z1, 0.f));
        }
    __syncthreads();

    v4f acc2[4] = {};
#pragma unroll
    for (int kt = 0; kt < 4; kt++)
#pragma unroll
        for (int mt = 0; mt < 4; mt++) {
            v8s a = *(const v8s*)&za[(mt * 16 + l15) * 136 + kt * 32 + q * 8];
            acc2[mt] = MFMA(a, b2[kt], acc2[mt]);
        }
    __syncthreads();

    {
        int col = w * 16 + l15;
        float b2c = em2b[col], w3c = em3w[col];
#pragma unroll
        for (int mt = 0; mt < 4; mt++)
#pragma unroll
            for (int r = 0; r < 4; r++) {
                float v = fmaxf(acc2[mt][r] + b2c, 0.f) * w3c;
#pragma unroll
                for (int off = 1; off < 16; off <<= 1) v += __shfl_xor(v, off);
                if (l15 == 0) part[w * 64 + mt * 16 + q * 4 + r] = v;
            }
    }
    __syncthreads();
    if (t < 64)
        out[e0 + t] = part[t] + part[64 + t] + part[128 + t] + part[192 + t]
                    + em3b[0];
}

// ------------------------------------------------------------ launch
extern "C" __attribute__((visibility("default")))
void kernel_launch(void* const* d_in, const int* in_sizes, int n_in,
                   void* d_out, int out_size, void* d_ws, size_t ws_size,
                   hipStream_t stream) {
    float* out = (float*)d_out;

    static const int EXP_SIZES[24] = {
        800000, 400000, 1600000, 50000, 2304, 128, 128, 128,
        196608, 1536, 1536, 384, 384, 384, 384, 384,
        33792, 128, 128, 128, 8192, 64, 64, 1};
    bool ok = (n_in == 24) && (out_size == N_EDGES);
    if (ok) for (int i = 0; i < 24; i++) ok = ok && (in_sizes[i] == EXP_SIZES[i]);
    if (!ok) {
        k_fill<<<(out_size + 255) / 256, 256, 0, stream>>>(out, out_size, 4.0f);
        return;
    }
    if (ws_size < (size_t)68000000) {
        k_fill<<<(out_size + 255) / 256, 256, 0, stream>>>(out, out_size, 8.0f);
        return;
    }

    const int* ei    = (const int*)d_in[1];
    const int* shock = (const int*)d_in[3];

    char* ws = (char*)d_ws;
    unsigned short* h_bf  = (unsigned short*)(ws + 0);          // 12,800,000
    unsigned short* g     = (unsigned short*)(ws + 12800000);   // 51,200,000
    float* al      = (float*)(ws + 64000000);                   // 1,600,000
    float* down    = (float*)(ws + 65600000);
    int*   deg     = (int*)  (ws + 65800000);
    int*   row_st  = (int*)  (ws + 66000000);
    int*   fill    = (int*)  (ws + 66200064);
    int*   csr_src = (int*)  (ws + 66400064);
    int*   flag    = (int*)  (ws + 67400064);
    unsigned short* gwt = (unsigned short*)(ws + 67400128);     // 393,216
    unsigned short* w1t = (unsigned short*)(ws + 67793344);     // 73,728
    unsigned short* w2t = (unsigned short*)(ws + 67867072);     // 16,384
    float* pool    = (float*)(ws + 67883456);                   // 11,272 f32
    unsigned short* vat = (unsigned short*)(ws + 67928544);     // 12,288 B

    float* cencw = pool + 0;    float* cencb = pool + 2304;
    float* cenlg = pool + 2432; float* cenlb = pool + 2560;
    float* cbias = pool + 5760; float* cbng  = pool + 6144;
    float* cbnb  = pool + 6528; float* cbnm  = pool + 6912;
    float* cbnv  = pool + 7296; float* cem1b = pool + 7680;
    float* cemlg = pool + 7808; float* cemlb = pool + 7936;
    float* cem2b = pool + 8064; float* cem3w = pool + 8128;
    float* cem3b = pool + 8192;
    float* va    = pool + 8200;    // [3][128][8]

    k_detect<<<1, 64, 0, stream>>>((const unsigned short*)d_in[0], flag);

    PrepArgs pa;
    pa.encw = d_in[4];  pa.encb = d_in[5];  pa.enlg = d_in[6];  pa.enlb = d_in[7];
    pa.gatw = d_in[8];  pa.asrc = d_in[9];  pa.adst = d_in[10]; pa.bias = d_in[11];
    pa.bng  = d_in[12]; pa.bnb  = d_in[13]; pa.bnm  = d_in[14]; pa.bnv  = d_in[15];
    pa.em1w = d_in[16]; pa.em1b = d_in[17]; pa.emlg = d_in[18]; pa.emlb = d_in[19];
    pa.em2w = d_in[20]; pa.em2b = d_in[21]; pa.em3w = d_in[22]; pa.em3b = d_in[23];
    k_prep<<<(PREP_ITEMS + 255) / 256, 256, 0, stream>>>(
        pa, pool, gwt, w1t, w2t, va, vat, down, deg, fill, flag);

    k_graph<<<(ETOT + 255) / 256, 256, 0, stream>>>(ei, shock, down, deg);
    k_scan<<<1, 1024, 0, stream>>>(deg, row_st);
    k_csr<<<(ETOT + 255) / 256, 256, 0, stream>>>(ei, row_st, fill, csr_src);
    k_encoder<<<512, 256, 0, stream>>>(d_in[0], flag, shock, down,
                                       cencw, cencb, cenlg, cenlb, va, h_bf, al);
    for (int i = 0; i < 3; i++) {
        k_aggregate<<<1536, 256, 0, stream>>>(h_bf, al, row_st, csr_src, g);
        k_gout<<<(N_NODES + 63) / 64, 256, 0, stream>>>(
            g, gwt + (size_t)i * 65536, cbias + i * 128,
            cbng + i * 128, cbnb + i * 128, cbnm + i * 128, cbnv + i * 128,
            vat + (size_t)(i + 1 < 3 ? i + 1 : 0) * 2048,
            h_bf, al, (i < 2) ? 1 : 0, (i < 2) ? 1 : 0);
    }
    k_edgemlp<<<N_EDGES / 64, 256, 0, stream>>>(
        h_bf, ei, d_in[2], flag, w1t, w2t,
        cem1b, cemlg, cemlb, cem2b, cem3w, cem3b, out);
}

// Round 9
// 628.997 us; speedup vs baseline: 1.0621x; 1.0621x over previous
//
#include <hip/hip_runtime.h>
#include <hip/hip_bf16.h>

// ShockPropagationGNN — round 8: encoder reverted to wave-per-node (barrier-
// free LN via shfl, al0 fused from registers). Keeps round-7 loop-body wins
// (logits fused into gout, grid-stride prefetched aggregate).

#define N_NODES 50000
#define N_EDGES 200000
#define ETOT    (N_EDGES + N_NODES)
#define HID     128
#define LN_EPS  1e-5f
#define NEG     0.2f

typedef __hip_bfloat16 bf16;
typedef __attribute__((ext_vector_type(8))) short v8s;
typedef __attribute__((ext_vector_type(4))) float v4f;
#define MFMA(a, b, c) __builtin_amdgcn_mfma_f32_16x16x32_bf16(a, b, c, 0, 0, 0)

__device__ __forceinline__ float b2f(unsigned short s) {
    return __uint_as_float(((unsigned int)s) << 16);
}
__device__ __forceinline__ unsigned short f2b(float f) {
    __hip_bfloat16 h = __float2bfloat16(f);
    return *reinterpret_cast<unsigned short*>(&h);
}
__device__ __forceinline__ unsigned int pack2(float a, float b) {
    return (unsigned int)f2b(a) | ((unsigned int)f2b(b) << 16);
}
__device__ __forceinline__ float pread(const void* p, size_t i, int isbf) {
    if (isbf) return b2f(((const unsigned short*)p)[i]);
    return ((const float*)p)[i];
}

__global__ void k_fill(float* out, int n, float v) {
    int i = blockIdx.x * blockDim.x + threadIdx.x;
    if (i < n) out[i] = v;
}

// ------------------------------------------------------------ dtype detect
__global__ void k_detect(const unsigned short* __restrict__ xbuf,
                         int* __restrict__ flag) {
    int sane = 0;
    for (int j = threadIdx.x; j < 4096; j += 64) {
        unsigned short v = xbuf[2 * j];
        int e = (v >> 7) & 0xFF;
        if (v == 0 || (e > 96 && e < 160)) sane++;
    }
    for (int off = 32; off > 0; off >>= 1) sane += __shfl_down(sane, off);
    if (threadIdx.x == 0) flag[0] = (sane * 10 >= 4096 * 9) ? 1 : 0;
}

// ------------------------------------------------------------ prep (fused)
struct PrepArgs {
    const void *encw, *encb, *enlg, *enlb, *gatw, *asrc, *adst, *bias,
               *bng, *bnb, *bnm, *bnv, *em1w, *em1b, *emlg, *emlb,
               *em2w, *em2b, *em3w, *em3b;
};
#define PREP_ITEMS (150000 + 8193 + 196608 + 36864 + 8192 + 3072 + 6144)
__global__ void k_prep(PrepArgs a, float* __restrict__ pool,
                       unsigned short* __restrict__ gwt,   // gw2t[L][c=128][hk=512]
                       unsigned short* __restrict__ w1t,
                       unsigned short* __restrict__ w2t,
                       float* __restrict__ va,             // [L][k=128][8] fp32
                       unsigned short* __restrict__ vat,   // [L][n=16][k=128] bf16
                       float* __restrict__ down, int* __restrict__ deg,
                       int* __restrict__ fill, const int* __restrict__ flag) {
    int i = blockIdx.x * 256 + threadIdx.x;
    int bf = flag[0];
    if (i < 150000) {
        int which = i / 50000, idx = i - which * 50000;
        if (which == 0) down[idx] = 0.f;
        else if (which == 1) deg[idx] = 0;
        else fill[idx] = 0;
        return;
    }
    i -= 150000;
    if (i < 8193) {
        const void* s; int off;
        if      (i < 2304) { s = a.encw; off = 0;    }
        else if (i < 2432) { s = a.encb; off = 2304; }
        else if (i < 2560) { s = a.enlg; off = 2432; }
        else if (i < 2688) { s = a.enlb; off = 2560; }
        else if (i < 4224) { s = a.asrc; off = 2688; }
        else if (i < 5760) { s = a.adst; off = 4224; }
        else if (i < 6144) { s = a.bias; off = 5760; }
        else if (i < 6528) { s = a.bng;  off = 6144; }
        else if (i < 6912) { s = a.bnb;  off = 6528; }
        else if (i < 7296) { s = a.bnm;  off = 6912; }
        else if (i < 7680) { s = a.bnv;  off = 7296; }
        else if (i < 7808) { s = a.em1b; off = 7680; }
        else if (i < 7936) { s = a.emlg; off = 7808; }
        else if (i < 8064) { s = a.emlb; off = 7936; }
        else if (i < 8128) { s = a.em2b; off = 8064; }
        else if (i < 8192) { s = a.em3w; off = 8128; }
        else               { s = a.em3b; off = 8192; }
        pool[i] = pread(s, i - off, bf);
        return;
    }
    i -= 8193;
    if (i < 196608) {   // gw2t[L][c][hk] = gat_w[L][k][h*128+c]
        int L = i >> 16, rem = i & 65535;
        int c = rem >> 9, hk = rem & 511, hh = hk >> 7, k = hk & 127;
        gwt[i] = f2b(pread(a.gatw,
            (size_t)L * 65536 + (size_t)k * 512 + hh * 128 + c, bf));
        return;
    }
    i -= 196608;
    if (i < 36864) {    // w1t[n=128][k=288] = em1_w[k][n], zero-pad k>=264
        int n = i / 288, k = i - n * 288;
        w1t[i] = (k < 264) ? f2b(pread(a.em1w, (size_t)k * 128 + n, bf)) : 0;
        return;
    }
    i -= 36864;
    if (i < 8192) {     // w2t[n=64][k=128] = em2_w[k][n]
        int n = i >> 7, k = i & 127;
        w2t[i] = f2b(pread(a.em2w, (size_t)k * 64 + n, bf));
        return;
    }
    i -= 8192;
    if (i < 3072) {     // va[L][k][j8] = sum_c W[L][k][h*128+c] * att[h][c]
        int L = i / 1024, rem = i - L * 1024;
        int k = rem >> 3, j8 = rem & 7, hh = j8 & 3, sd = j8 >> 2;
        const void* att = sd ? a.adst : a.asrc;
        float s = 0.f;
        for (int c = 0; c < 128; c++)
            s += pread(a.gatw, (size_t)L * 65536 + (size_t)k * 512 + hh * 128 + c, bf)
               * pread(att, (size_t)L * 512 + hh * 128 + c, bf);
        va[i] = s;
        return;
    }
    i -= 3072;
    if (i < 6144) {     // vat[L][n=16][k=128] bf16, n<8 real (j), else 0
        int L = i / 2048, rem = i - L * 2048;
        int n = rem >> 7, k = rem & 127;
        if (n >= 8) { vat[i] = 0; return; }
        int hh = n & 3, sd = n >> 2;
        const void* att = sd ? a.adst : a.asrc;
        float s = 0.f;
        for (int c = 0; c < 128; c++)
            s += pread(a.gatw, (size_t)L * 65536 + (size_t)k * 512 + hh * 128 + c, bf)
               * pread(att, (size_t)L * 512 + hh * 128 + c, bf);
        vat[i] = f2b(s);
    }
}

// ------------------------------------------------------------ graph build
__global__ void k_graph(const int* __restrict__ ei, const int* __restrict__ shock,
                        float* __restrict__ down, int* __restrict__ deg) {
    int e = blockIdx.x * blockDim.x + threadIdx.x;
    if (e < ETOT) {
        int d = (e < N_EDGES) ? ei[N_EDGES + e] : (e - N_EDGES);
        atomicAdd(&deg[d], 1);
        if (e < N_EDGES && shock[ei[e]] != 0) down[d] = 1.f;
    }
}

__global__ __launch_bounds__(1024) void k_scan(
        const int* __restrict__ deg, int* __restrict__ row_start) {
    __shared__ int wsum[16];
    __shared__ int wexcl[16];
    const int PER = 49;
    int t = threadIdx.x, lane = t & 63, wid = t >> 6;
    int base = t * PER;
    int tot = 0;
    for (int i = 0; i < PER; i++) {
        int idx = base + i;
        if (idx < N_NODES) tot += deg[idx];
    }
    int inc = tot;
#pragma unroll
    for (int off = 1; off < 64; off <<= 1) {
        int v = __shfl_up(inc, off);
        if (lane >= off) inc += v;
    }
    if (lane == 63) wsum[wid] = inc;
    __syncthreads();
    if (wid == 0) {
        int wv = (lane < 16) ? wsum[lane] : 0;
        int winc = wv;
#pragma unroll
        for (int off = 1; off < 16; off <<= 1) {
            int v = __shfl_up(winc, off);
            if (lane >= off) winc += v;
        }
        if (lane < 16) wexcl[lane] = winc - wv;
    }
    __syncthreads();
    int run = wexcl[wid] + (inc - tot);
    for (int i = 0; i < PER; i++) {
        int idx = base + i;
        if (idx < N_NODES) {
            row_start[idx] = run;
            run += deg[idx];
        }
    }
    if (t == 0) row_start[N_NODES] = ETOT;
}

__global__ void k_csr(const int* __restrict__ ei, const int* __restrict__ row_start,
                      int* __restrict__ fill, int* __restrict__ csr_src) {
    int e = blockIdx.x * blockDim.x + threadIdx.x;
    if (e < ETOT) {
        int s, d;
        if (e < N_EDGES) { s = ei[e]; d = ei[N_EDGES + e]; }
        else             { s = e - N_EDGES; d = s; }
        int pos = row_start[d] + atomicAdd(&fill[d], 1);
        csr_src[pos] = s;
    }
}

// ------------------------------------------------------------ encoder -> h, al0
// Wave per node (4 nodes / 256-thr block). Lane l: channels 2l, 2l+1.
// x broadcast via shfl, LN via shfl_xor — one barrier total (weight staging).
__global__ __launch_bounds__(256) void k_encoder(
        const void* __restrict__ xraw, const int* __restrict__ flag,
        const int* __restrict__ shock, const float* __restrict__ down,
        const float* __restrict__ enc_w, const float* __restrict__ enc_b,
        const float* __restrict__ ln_g, const float* __restrict__ ln_b,
        const float* __restrict__ va0,
        unsigned short* __restrict__ h, float* __restrict__ al) {
    __shared__ float sw[2304];
    __shared__ float sp[384];      // enc_b | ln_g | ln_b
    __shared__ float sva[1024];
    int t = threadIdx.x;
    for (int i = t; i < 2304; i += 256) sw[i] = enc_w[i];
    for (int i = t; i < 1024; i += 256) sva[i] = va0[i];
    if (t < 128)      sp[t] = enc_b[t];
    else if (t < 256) sp[t] = ln_g[t - 128];
    if (t < 128)      sp[256 + t] = ln_b[t];
    __syncthreads();

    int w = t >> 6, l = t & 63;
    int n = blockIdx.x * 4 + w;
    int bf = flag[0];
    int c0 = 2 * l, c1 = c0 + 1;

    float xv = (l < 16) ? pread(xraw, (size_t)n * 16 + l, bf) : 0.f;
    float xs = (float)shock[n];
    float xd = down[n];

    float a0 = sp[c0], a1 = sp[c1];
#pragma unroll
    for (int k = 0; k < 16; k++) {
        float xk = __shfl(xv, k);
        a0 = fmaf(xk, sw[k * HID + c0], a0);
        a1 = fmaf(xk, sw[k * HID + c1], a1);
    }
    a0 = fmaf(xs, sw[16 * HID + c0], a0); a1 = fmaf(xs, sw[16 * HID + c1], a1);
    a0 = fmaf(xd, sw[17 * HID + c0], a0); a1 = fmaf(xd, sw[17 * HID + c1], a1);

    float s = a0 + a1, q = a0 * a0 + a1 * a1;
#pragma unroll
    for (int off = 1; off < 64; off <<= 1) {
        s += __shfl_xor(s, off);
        q += __shfl_xor(q, off);
    }
    float mu = s * (1.f / 128.f);
    float var = q * (1.f / 128.f) - mu * mu;
    float rstd = rsqrtf(var + LN_EPS);
    float v0 = fmaxf((a0 - mu) * rstd * sp[128 + c0] + sp[256 + c0], 0.f);
    float v1 = fmaxf((a1 - mu) * rstd * sp[128 + c1] + sp[256 + c1], 0.f);
    *(unsigned int*)&h[(size_t)n * HID + c0] = pack2(v0, v1);

    // al0 from registers: p[j] = sum_c h[c] * va0[c][j]
    float p[8];
#pragma unroll
    for (int j = 0; j < 8; j++)
        p[j] = v0 * sva[c0 * 8 + j] + v1 * sva[c1 * 8 + j];
#pragma unroll
    for (int j = 0; j < 8; j++)
#pragma unroll
        for (int off = 1; off < 64; off <<= 1) p[j] += __shfl_xor(p[j], off);
    if (l < 8) al[(size_t)n * 8 + l] = p[l];
}

// ------------------------------------------------------------ aggregation -> g
__global__ __launch_bounds__(256) void k_aggregate(
        const unsigned short* __restrict__ h, const float* __restrict__ al,
        const int* __restrict__ row_start, const int* __restrict__ csr_src,
        unsigned short* __restrict__ g) {
    int w = threadIdx.x >> 6, l = threadIdx.x & 63;
    for (int n = blockIdx.x * 4 + w; n < N_NODES; n += gridDim.x * 4) {
        int r0 = row_start[n], r1 = row_start[n + 1];
        float4 ad = *(const float4*)(al + (size_t)n * 8 + 4);
        float den[4] = {};
        float acc[4][2] = {};
        int s = csr_src[r0];
        float4 as = *(const float4*)(al + (size_t)s * 8);
        unsigned int hv = *(const unsigned int*)&h[(size_t)s * 128 + 2 * l];
        for (int j = r0; j < r1; j++) {
            int s2 = s; float4 as2 = as; unsigned int hv2 = hv;
            if (j + 1 < r1) {
                s2 = csr_src[j + 1];
                as2 = *(const float4*)(al + (size_t)s2 * 8);
                hv2 = *(const unsigned int*)&h[(size_t)s2 * 128 + 2 * l];
            }
            float h0 = b2f(hv & 0xffff), h1 = b2f(hv >> 16);
            float lg[4] = {as.x + ad.x, as.y + ad.y, as.z + ad.z, as.w + ad.w};
#pragma unroll
            for (int hh = 0; hh < 4; hh++) {
                float a = lg[hh];
                a = (a >= 0.f) ? a : NEG * a;
                float we = __expf(a);
                den[hh] += we;
                acc[hh][0] = fmaf(we, h0, acc[hh][0]);
                acc[hh][1] = fmaf(we, h1, acc[hh][1]);
            }
            s = s2; as = as2; hv = hv2;
        }
#pragma unroll
        for (int hh = 0; hh < 4; hh++) {
            float sc = 0.25f / (den[hh] + 1e-16f);
            *(unsigned int*)&g[(size_t)n * 512 + hh * 128 + 2 * l] =
                pack2(acc[hh][0] * sc, acc[hh][1] * sc);
        }
    }
}

// ------------------------------------------------------------ output GEMM + al
__global__ __launch_bounds__(256, 2) void k_gout(
        const unsigned short* __restrict__ g, const unsigned short* __restrict__ Bt,
        const float* __restrict__ bias,
        const float* __restrict__ bn_g, const float* __restrict__ bn_b,
        const float* __restrict__ bn_m, const float* __restrict__ bn_v,
        const unsigned short* __restrict__ vatL,
        unsigned short* __restrict__ h, float* __restrict__ al,
        int relu_flag, int do_al) {
    __shared__ __align__(16) unsigned short As[2][64 * 136];
    int t = threadIdx.x;
    int lane = t & 63, w = t >> 6, l15 = lane & 15, q = lane >> 4;
    int m0 = blockIdx.x * 64;
    int c0 = w * 32 + 2 * l15, c1 = c0 + 1;

#pragma unroll
    for (int it = 0; it < 4; it++) {
        int u = t + it * 256;
        int row = u >> 4, ch = u & 15;
        v8s val = {0, 0, 0, 0, 0, 0, 0, 0};
        if (m0 + row < N_NODES)
            val = *(const v8s*)&g[(size_t)(m0 + row) * 512 + ch * 8];
        *(v8s*)&As[0][row * 136 + ch * 8] = val;
    }

    v4f acc[4][2] = {};
    for (int kc = 0; kc < 4; kc++) {
        v8s b[2][4];
#pragma unroll
        for (int nt = 0; nt < 2; nt++)
#pragma unroll
            for (int kt = 0; kt < 4; kt++)
                b[nt][kt] = *(const v8s*)&Bt[(size_t)(c0 + nt) * 512
                                             + kc * 128 + kt * 32 + q * 8];
        v8s st[4];
        if (kc < 3) {
#pragma unroll
            for (int it = 0; it < 4; it++) {
                int u = t + it * 256;
                int row = u >> 4, ch = u & 15;
                v8s val = {0, 0, 0, 0, 0, 0, 0, 0};
                if (m0 + row < N_NODES)
                    val = *(const v8s*)&g[(size_t)(m0 + row) * 512
                                          + (kc + 1) * 128 + ch * 8];
                st[it] = val;
            }
        }
        __syncthreads();
        const unsigned short* Ab = As[kc & 1];
#pragma unroll
        for (int kt = 0; kt < 4; kt++)
#pragma unroll
            for (int mt = 0; mt < 4; mt++) {
                v8s a = *(const v8s*)&Ab[(mt * 16 + l15) * 136 + kt * 32 + q * 8];
                acc[mt][0] = MFMA(a, b[0][kt], acc[mt][0]);
                acc[mt][1] = MFMA(a, b[1][kt], acc[mt][1]);
            }
        if (kc < 3) {
#pragma unroll
            for (int it = 0; it < 4; it++) {
                int u = t + it * 256;
                int row = u >> 4, ch = u & 15;
                *(v8s*)&As[(kc + 1) & 1][row * 136 + ch * 8] = st[it];
            }
        }
    }

    float rs0 = rsqrtf(bn_v[c0] + LN_EPS) * bn_g[c0];
    float sh0 = bn_b[c0] + (bias[c0] - bn_m[c0]) * rs0;
    float rs1 = rsqrtf(bn_v[c1] + LN_EPS) * bn_g[c1];
    float sh1 = bn_b[c1] + (bias[c1] - bn_m[c1]) * rs1;
    unsigned int hp[4][4];
#pragma unroll
    for (int mt = 0; mt < 4; mt++)
#pragma unroll
        for (int r = 0; r < 4; r++) {
            float v0 = acc[mt][0][r] * rs0 + sh0;
            float v1 = acc[mt][1][r] * rs1 + sh1;
            if (relu_flag) { v0 = fmaxf(v0, 0.f); v1 = fmaxf(v1, 0.f); }
            hp[mt][r] = pack2(v0, v1);
            int node = m0 + mt * 16 + q * 4 + r;
            if (node < N_NODES)
                *(unsigned int*)&h[(size_t)node * 128 + c0] = hp[mt][r];
        }

    if (do_al) {
        __syncthreads();
#pragma unroll
        for (int mt = 0; mt < 4; mt++)
#pragma unroll
            for (int r = 0; r < 4; r++)
                *(unsigned int*)&As[0][(mt * 16 + q * 4 + r) * 136 + c0] = hp[mt][r];
        __syncthreads();
        v8s bv[4];
#pragma unroll
        for (int kt = 0; kt < 4; kt++)
            bv[kt] = *(const v8s*)&vatL[l15 * 128 + kt * 32 + q * 8];
        v4f aal = {};
#pragma unroll
        for (int kt = 0; kt < 4; kt++) {
            v8s a = *(const v8s*)&As[0][(w * 16 + l15) * 136 + kt * 32 + q * 8];
            aal = MFMA(a, bv[kt], aal);
        }
        if (l15 < 8) {
#pragma unroll
            for (int r = 0; r < 4; r++) {
                int node = m0 + w * 16 + q * 4 + r;
                if (node < N_NODES) al[(size_t)node * 8 + l15] = aal[r];
            }
        }
    }
}

// ------------------------------------------------------------ edge MLP (MFMA)
__global__ __launch_bounds__(256, 4) void k_edgemlp(
        const unsigned short* __restrict__ h, const int* __restrict__ ei,
        const void* __restrict__ eraw, const int* __restrict__ flag,
        const unsigned short* __restrict__ w1t, const unsigned short* __restrict__ w2t,
        const float* __restrict__ em1b, const float* __restrict__ lng,
        const float* __restrict__ lnb, const float* __restrict__ em2b,
        const float* __restrict__ em3w, const float* __restrict__ em3b,
        float* __restrict__ out) {
    __shared__ __align__(16) unsigned short in_s[64 * 296];
    __shared__ float sums[64][4][2];
    __shared__ float stats[64][2];
    __shared__ int   idx_s[128];
    unsigned short* za = in_s;
    float* part = &sums[0][0][0];

    int t = threadIdx.x;
    int lane = t & 63, w = t >> 6, l15 = lane & 15, q = lane >> 4;
    int e0 = blockIdx.x * 64;
    int bf = flag[0];
    int c0 = w * 32 + 2 * l15, c1 = c0 + 1;

    v8s b1[2][9];
#pragma unroll
    for (int nt = 0; nt < 2; nt++)
#pragma unroll
        for (int kt = 0; kt < 9; kt++)
            b1[nt][kt] = *(const v8s*)&w1t[(size_t)(c0 + nt) * 288 + kt * 32 + q * 8];
    v8s b2[4];
#pragma unroll
    for (int kt = 0; kt < 4; kt++)
        b2[kt] = *(const v8s*)&w2t[(size_t)(w * 16 + l15) * 128 + kt * 32 + q * 8];

    float bc0 = em1b[c0], bc1 = em1b[c1];
    float lg0 = lng[c0], lg1 = lng[c1], lb0 = lnb[c0], lb1 = lnb[c1];

    if (t < 64) {
        idx_s[t * 2]     = ei[e0 + t];
        idx_s[t * 2 + 1] = ei[N_EDGES + e0 + t];
    }
    __syncthreads();

    for (int idx = t; idx < 64 * 36; idx += 256) {
        int row = idx / 36, c = idx - row * 36;
        v8s val = {0, 0, 0, 0, 0, 0, 0, 0};
        if (c < 32) {
            int node = idx_s[row * 2 + (c >> 4)];
            val = *(const v8s*)&h[(size_t)node * 128 + (c & 15) * 8];
        } else if (c == 32) {
            size_t eb = (size_t)(e0 + row) * 8;
            if (bf) {
                val = *(const v8s*)((const unsigned short*)eraw + eb);
            } else {
                short tmp[8];
#pragma unroll
                for (int j = 0; j < 8; j++)
                    tmp[j] = (short)f2b(((const float*)eraw)[eb + j]);
                val = *(const v8s*)tmp;
            }
        }
        *(v8s*)&in_s[row * 296 + c * 8] = val;
    }
    __syncthreads();

    v4f acc1[4][2] = {};
#pragma unroll
    for (int kt = 0; kt < 9; kt++)
#pragma unroll
        for (int mt = 0; mt < 4; mt++) {
            v8s a = *(const v8s*)&in_s[(mt * 16 + l15) * 296 + kt * 32 + q * 8];
            acc1[mt][0] = MFMA(a, b1[0][kt], acc1[mt][0]);
            acc1[mt][1] = MFMA(a, b1[1][kt], acc1[mt][1]);
        }

#pragma unroll
    for (int mt = 0; mt < 4; mt++)
#pragma unroll
        for (int r = 0; r < 4; r++) {
            float v0 = acc1[mt][0][r] + bc0;
            float v1 = acc1[mt][1][r] + bc1;
            float s = v0 + v1;
            float qq = v0 * v0 + v1 * v1;
#pragma unroll
            for (int off = 1; off < 16; off <<= 1) {
                s  += __shfl_xor(s, off);
                qq += __shfl_xor(qq, off);
            }
            if (l15 == 0) {
                sums[mt * 16 + q * 4 + r][w][0] = s;
                sums[mt * 16 + q * 4 + r][w][1] = qq;
            }
        }
    __syncthreads();
    if (t < 64) {
        float S = sums[t][0][0] + sums[t][1][0] + sums[t][2][0] + sums[t][3][0];
        float Q = sums[t][0][1] + sums[t][1][1] + sums[t][2][1] + sums[t][3][1];
        float mu = S * (1.f / 128.f);
        float var = Q * (1.f / 128.f) - mu * mu;
        stats[t][0] = mu;
        stats[t][1] = rsqrtf(var + LN_EPS);
    }
    __syncthreads();

#pragma unroll
    for (int mt = 0; mt < 4; mt++)
#pragma unroll
        for (int r = 0; r < 4; r++) {
            int row = mt * 16 + q * 4 + r;
            float mu = stats[row][0], rstd = stats[row][1];
            float z0 = (acc1[mt][0][r] + bc0 - mu) * rstd * lg0 + lb0;
            float z1 = (acc1[mt][1][r] + bc1 - mu) * rstd * lg1 + lb1;
            *(unsigned int*)&za[row * 136 + c0] =
                pack2(fmaxf(z0, 0.f), fmaxf(z1, 0.f));
        }
    __syncthreads();

    v4f acc2[4] = {};
#pragma unroll
    for (int kt = 0; kt < 4; kt++)
#pragma unroll
        for (int mt = 0; mt < 4; mt++) {
            v8s a = *(const v8s*)&za[(mt * 16 + l15) * 136 + kt * 32 + q * 8];
            acc2[mt] = MFMA(a, b2[kt], acc2[mt]);
        }
    __syncthreads();

    {
        int col = w * 16 + l15;
        float b2c = em2b[col], w3c = em3w[col];
#pragma unroll
        for (int mt = 0; mt < 4; mt++)
#pragma unroll
            for (int r = 0; r < 4; r++) {
                float v = fmaxf(acc2[mt][r] + b2c, 0.f) * w3c;
#pragma unroll
                for (int off = 1; off < 16; off <<= 1) v += __shfl_xor(v, off);
                if (l15 == 0) part[w * 64 + mt * 16 + q * 4 + r] = v;
            }
    }
    __syncthreads();
    if (t < 64)
        out[e0 + t] = part[t] + part[64 + t] + part[128 + t] + part[192 + t]
                    + em3b[0];
}

// ------------------------------------------------------------ launch
extern "C" __attribute__((visibility("default")))
void kernel_launch(void* const* d_in, const int* in_sizes, int n_in,
                   void* d_out, int out_size, void* d_ws, size_t ws_size,
                   hipStream_t stream) {
    float* out = (float*)d_out;

    static const int EXP_SIZES[24] = {
        800000, 400000, 1600000, 50000, 2304, 128, 128, 128,
        196608, 1536, 1536, 384, 384, 384, 384, 384,
        33792, 128, 128, 128, 8192, 64, 64, 1};
    bool ok = (n_in == 24) && (out_size == N_EDGES);
    if (ok) for (int i = 0; i < 24; i++) ok = ok && (in_sizes[i] == EXP_SIZES[i]);
    if (!ok) {
        k_fill<<<(out_size + 255) / 256, 256, 0, stream>>>(out, out_size, 4.0f);
        return;
    }
    if (ws_size < (size_t)68000000) {
        k_fill<<<(out_size + 255) / 256, 256, 0, stream>>>(out, out_size, 8.0f);
        return;
    }

    const int* ei    = (const int*)d_in[1];
    const int* shock = (const int*)d_in[3];

    char* ws = (char*)d_ws;
    unsigned short* h_bf  = (unsigned short*)(ws + 0);          // 12,800,000
    unsigned short* g     = (unsigned short*)(ws + 12800000);   // 51,200,000
    float* al      = (float*)(ws + 64000000);                   // 1,600,000
    float* down    = (float*)(ws + 65600000);
    int*   deg     = (int*)  (ws + 65800000);
    int*   row_st  = (int*)  (ws + 66000000);
    int*   fill    = (int*)  (ws + 66200064);
    int*   csr_src = (int*)  (ws + 66400064);
    int*   flag    = (int*)  (ws + 67400064);
    unsigned short* gwt = (unsigned short*)(ws + 67400128);     // 393,216
    unsigned short* w1t = (unsigned short*)(ws + 67793344);     // 73,728
    unsigned short* w2t = (unsigned short*)(ws + 67867072);     // 16,384
    float* pool    = (float*)(ws + 67883456);                   // 11,272 f32
    unsigned short* vat = (unsigned short*)(ws + 67928544);     // 12,288 B

    float* cencw = pool + 0;    float* cencb = pool + 2304;
    float* cenlg = pool + 2432; float* cenlb = pool + 2560;
    float* cbias = pool + 5760; float* cbng  = pool + 6144;
    float* cbnb  = pool + 6528; float* cbnm  = pool + 6912;
    float* cbnv  = pool + 7296; float* cem1b = pool + 7680;
    float* cemlg = pool + 7808; float* cemlb = pool + 7936;
    float* cem2b = pool + 8064; float* cem3w = pool + 8128;
    float* cem3b = pool + 8192;
    float* va    = pool + 8200;    // [3][128][8]

    k_detect<<<1, 64, 0, stream>>>((const unsigned short*)d_in[0], flag);

    PrepArgs pa;
    pa.encw = d_in[4];  pa.encb = d_in[5];  pa.enlg = d_in[6];  pa.enlb = d_in[7];
    pa.gatw = d_in[8];  pa.asrc = d_in[9];  pa.adst = d_in[10]; pa.bias = d_in[11];
    pa.bng  = d_in[12]; pa.bnb  = d_in[13]; pa.bnm  = d_in[14]; pa.bnv  = d_in[15];
    pa.em1w = d_in[16]; pa.em1b = d_in[17]; pa.emlg = d_in[18]; pa.emlb = d_in[19];
    pa.em2w = d_in[20]; pa.em2b = d_in[21]; pa.em3w = d_in[22]; pa.em3b = d_in[23];
    k_prep<<<(PREP_ITEMS + 255) / 256, 256, 0, stream>>>(
        pa, pool, gwt, w1t, w2t, va, vat, down, deg, fill, flag);

    k_graph<<<(ETOT + 255) / 256, 256, 0, stream>>>(ei, shock, down, deg);
    k_scan<<<1, 1024, 0, stream>>>(deg, row_st);
    k_csr<<<(ETOT + 255) / 256, 256, 0, stream>>>(ei, row_st, fill, csr_src);
    k_encoder<<<N_NODES / 4, 256, 0, stream>>>(
        d_in[0], flag, shock, down, cencw, cencb, cenlg, cenlb, va, h_bf, al);
    for (int i = 0; i < 3; i++) {
        k_aggregate<<<1536, 256, 0, stream>>>(h_bf, al, row_st, csr_src, g);
        k_gout<<<(N_NODES + 63) / 64, 256, 0, stream>>>(
            g, gwt + (size_t)i * 65536, cbias + i * 128,
            cbng + i * 128, cbnb + i * 128, cbnm + i * 128, cbnv + i * 128,
            vat + (size_t)(i + 1 < 3 ? i + 1 : 0) * 2048,
            h_bf, al, (i < 2) ? 1 : 0, (i < 2) ? 1 : 0);
    }
    k_edgemlp<<<N_EDGES / 64, 256, 0, stream>>>(
        h_bf, ei, d_in[2], flag, w1t, w2t,
        cem1b, cemlg, cemlb, cem2b, cem3w, cem3b, out);
}